// Round 3
// baseline (163.611 us; speedup 1.0000x reference)
//
#include <hip/hip_runtime.h>
#include <hip/hip_bf16.h>

// Problem constants (fixed by setup_inputs): B=4, C=4, H=W=64, K=8192
#define BB 4
#define CC 4
#define NN 4096            // H*W
#define KK 8192
#define NPOS 16384         // B*N

// Output layout (FLOAT32 elements): [0..65535] dec_in; [65536] codebook_loss;
// [65537] commitment_loss; [65538..81921] closest_idx
#define OUT_LOSS 65536
#define OUT_IDX  65538

// ws layout (floats): [0..KK-1] codebook norms; [KK],[KK+1] loss accumulators

// Monotone float->uint map: preserves < ordering for all finite floats.
__device__ __forceinline__ unsigned int fkey(float s) {
    unsigned int u = __float_as_uint(s);
    return (u & 0x80000000u) ? ~u : (u | 0x80000000u);
}

__global__ __launch_bounds__(256) void vq_prep(const float* __restrict__ cb,
                                               float* __restrict__ ws) {
    int k = blockIdx.x * 256 + threadIdx.x;   // grid 32*256 == KK exactly
    const float* e = cb + k * 4;
    // numpy style: each product rounded, then sequential adds (no fma contraction)
    float n0 = __fmul_rn(e[0], e[0]);
    n0 = __fadd_rn(n0, __fmul_rn(e[1], e[1]));
    n0 = __fadd_rn(n0, __fmul_rn(e[2], e[2]));
    n0 = __fadd_rn(n0, __fmul_rn(e[3], e[3]));
    ws[k] = n0;
    if (blockIdx.x == 0 && threadIdx.x < 2) ws[KK + threadIdx.x] = 0.0f;
}

__global__ __launch_bounds__(256) void vq_search(const float* __restrict__ x,
                                                 const float* __restrict__ pw,
                                                 const float* __restrict__ pb,
                                                 const float* __restrict__ cb,
                                                 const float* __restrict__ qw,
                                                 const float* __restrict__ qb,
                                                 float* __restrict__ ws,
                                                 float* __restrict__ out) {
    __shared__ unsigned long long keys[4][8][64];  // [wave][pos][lane]
    __shared__ float lsum[32];

    const int tid  = threadIdx.x;
    const int lane = tid & 63;
    const int wave = tid >> 6;
    const int pos0 = (blockIdx.x * 4 + wave) * 8;  // 32 positions per block

    // ---- prequant q for the wave's 8 positions (all lanes, wave-uniform loads) ----
    float q[8][4], qq[8];
#pragma unroll
    for (int p = 0; p < 8; ++p) {
        int pos = pos0 + p;
        int b = pos >> 12, n = pos & 4095;
        const float* xb = x + b * (CC * NN) + n;
        float xv0 = xb[0], xv1 = xb[NN], xv2 = xb[2 * NN], xv3 = xb[3 * NN];
#pragma unroll
        for (int o = 0; o < 4; ++o) {
            // einsum "bchw,oc->bohw": BLAS-style fma chain, ascending c
            float t = fmaf(pw[o * 4 + 0], xv0, 0.0f);
            t = fmaf(pw[o * 4 + 1], xv1, t);
            t = fmaf(pw[o * 4 + 2], xv2, t);
            t = fmaf(pw[o * 4 + 3], xv3, t);
            q[p][o] = __fadd_rn(t, pb[o]);
        }
        // ||q||^2 numpy-style: rounded products, sequential adds
        float s = __fmul_rn(q[p][0], q[p][0]);
        s = __fadd_rn(s, __fmul_rn(q[p][1], q[p][1]));
        s = __fadd_rn(s, __fmul_rn(q[p][2], q[p][2]));
        s = __fadd_rn(s, __fmul_rn(q[p][3], q[p][3]));
        qq[p] = s;
    }

    // ---- strided scan over codebook: lane handles k = lane, lane+64, ... ----
    float best[8];
    int   bi[8];
#pragma unroll
    for (int p = 0; p < 8; ++p) { best[p] = __int_as_float(0x7f800000); bi[p] = 0; }

    const float4* cb4 = (const float4*)cb;
    const float*  nrm = ws;

    for (int k = lane; k < KK; k += 64) {
        float4 e  = cb4[k];
        float  nk = nrm[k];
#pragma unroll
        for (int p = 0; p < 8; ++p) {
            float d = fmaf(q[p][0], e.x, 0.0f);       // BLAS-style dot, ascending c
            d = fmaf(q[p][1], e.y, d);
            d = fmaf(q[p][2], e.z, d);
            d = fmaf(q[p][3], e.w, d);
            // reference assoc: (qq - 2*dot) + nk ; 2*dot exact, fma == sub rounding
            float s = __fadd_rn(fmaf(-2.0f, d, qq[p]), nk);
            if (s < best[p]) { best[p] = s; bi[p] = k; }  // strict <: first k wins
        }
    }

    // ---- publish per-lane winners as packed keys; min-key == np.argmin semantics ----
#pragma unroll
    for (int p = 0; p < 8; ++p)
        keys[wave][p][lane] =
            ((unsigned long long)fkey(best[p]) << 32) | (unsigned int)bi[p];
    __syncthreads();

    // ---- one thread per position: reduce 64 keys, then full epilogue ----
    if (tid < 32) {
        int w = tid >> 3, p = tid & 7;
        unsigned long long bk = ~0ull;
#pragma unroll 4
        for (int i = 0; i < 64; ++i) {
            unsigned long long c = keys[w][p][i ^ tid];    // XOR spreads LDS banks
            bk = (c < bk) ? c : bk;
        }
        int idx = (int)(bk & 0xFFFFFFFFull);

        int pos = (blockIdx.x * 4 + w) * 8 + p;
        int b = pos >> 12, n = pos & 4095;
        float4 e = cb4[idx];

        const float* xb = x + b * (CC * NN) + n;
        float xv0 = xb[0], xv1 = xb[NN], xv2 = xb[2 * NN], xv3 = xb[3 * NN];

        // straight-through (forward): st = x + (quant - x), matching reference fp ops
        float s0 = __fadd_rn(xv0, __fsub_rn(e.x, xv0));
        float s1 = __fadd_rn(xv1, __fsub_rn(e.y, xv1));
        float s2 = __fadd_rn(xv2, __fsub_rn(e.z, xv2));
        float s3 = __fadd_rn(xv3, __fsub_rn(e.w, xv3));

        // postquant 1x1 conv -> float32 output
#pragma unroll
        for (int o = 0; o < 4; ++o) {
            float t = fmaf(qw[o * 4 + 0], s0, 0.0f);
            t = fmaf(qw[o * 4 + 1], s1, t);
            t = fmaf(qw[o * 4 + 2], s2, t);
            t = fmaf(qw[o * 4 + 3], s3, t);
            t = __fadd_rn(t, qb[o]);
            out[b * (CC * NN) + o * NN + n] = t;
        }

        // loss partial: sum_c (quant - x)^2 (both losses identical in forward)
        float d0 = __fsub_rn(e.x, xv0), d1 = __fsub_rn(e.y, xv1);
        float d2 = __fsub_rn(e.z, xv2), d3 = __fsub_rn(e.w, xv3);
        float lp = __fmul_rn(d0, d0);
        lp = __fadd_rn(lp, __fmul_rn(d1, d1));
        lp = __fadd_rn(lp, __fmul_rn(d2, d2));
        lp = __fadd_rn(lp, __fmul_rn(d3, d3));
        lsum[tid] = lp;

        // index output as float32 (harness reads float; ref may be bf16-rounded,
        // slack |8191 - bf16(8191)| = 1..32 << 163.84 threshold)
        out[OUT_IDX + b * NN + n] = (float)idx;
    }
    __syncthreads();

    if (tid == 0) {
        float s = 0.0f;
        for (int i = 0; i < 32; ++i) s += lsum[i];
        s *= (1.0f / (float)(NPOS * CC));
        atomicAdd(&ws[KK + 0], s);
        atomicAdd(&ws[KK + 1], s);
    }
}

__global__ void vq_fin(const float* __restrict__ ws, float* __restrict__ out) {
    if (threadIdx.x < 2)
        out[OUT_LOSS + threadIdx.x] = ws[KK + threadIdx.x];
}

extern "C" void kernel_launch(void* const* d_in, const int* in_sizes, int n_in,
                              void* d_out, int out_size, void* d_ws, size_t ws_size,
                              hipStream_t stream) {
    const float* x  = (const float*)d_in[0];
    const float* pw = (const float*)d_in[1];
    const float* pb = (const float*)d_in[2];
    const float* cb = (const float*)d_in[3];
    const float* qw = (const float*)d_in[4];
    const float* qb = (const float*)d_in[5];
    float* out = (float*)d_out;
    float* ws  = (float*)d_ws;

    vq_prep<<<KK / 256, 256, 0, stream>>>(cb, ws);
    vq_search<<<NPOS / 32, 256, 0, stream>>>(x, pw, pb, cb, qw, qb, ws, out);
    vq_fin<<<1, 64, 0, stream>>>(ws, out);
}

// Round 4
// 100.116 us; speedup vs baseline: 1.6342x; 1.6342x over previous
//
#include <hip/hip_runtime.h>

// Problem constants (fixed by setup_inputs): B=4, C=4, H=W=64, K=8192
#define BB 4
#define CC 4
#define NN 4096            // H*W
#define KK 8192
#define NPOS 16384         // B*N
#define SLICES 4
#define SLICE_K (KK / SLICES)   // 2048

// Output layout (float32 elements): [0..65535] dec_in; [65536] codebook_loss;
// [65537] commitment_loss; [65538..81921] closest_idx
#define OUT_LOSS 65536
#define OUT_IDX  65538

// ws layout: bytes [0 .. 512KB): u64 partial keys [NPOS][SLICES];
//            bytes [512KB ..): float loss partials [64]
#define LOSS_BYTE_OFF (NPOS * SLICES * 8)

// Monotone float->uint map: preserves < ordering for all finite floats.
__device__ __forceinline__ unsigned int fkey(float s) {
    unsigned int u = __float_as_uint(s);
    return (u & 0x80000000u) ? ~u : (u | 0x80000000u);
}

__global__ __launch_bounds__(256) void vq_search(const float* __restrict__ x,
                                                 const float* __restrict__ pw,
                                                 const float* __restrict__ pb,
                                                 const float* __restrict__ cb,
                                                 unsigned long long* __restrict__ keys_ws) {
    __shared__ unsigned long long keys[4][8][64];  // [wave][pos][lane] = 16 KB

    const int tid   = threadIdx.x;
    const int lane  = tid & 63;
    const int wave  = tid >> 6;
    const int slice = blockIdx.x & (SLICES - 1);
    const int pg    = blockIdx.x >> 2;             // 0..511 position-group
    const int pos0  = (pg * 4 + wave) * 8;         // wave owns 8 positions
    const int k0    = slice * SLICE_K;

    // ---- prequant q for the wave's 8 positions (all lanes, wave-uniform loads) ----
    float q[8][4], qq[8];
#pragma unroll
    for (int p = 0; p < 8; ++p) {
        int pos = pos0 + p;
        int b = pos >> 12, n = pos & 4095;
        const float* xb = x + b * (CC * NN) + n;
        float xv0 = xb[0], xv1 = xb[NN], xv2 = xb[2 * NN], xv3 = xb[3 * NN];
#pragma unroll
        for (int o = 0; o < 4; ++o) {
            // einsum "bchw,oc->bohw": BLAS-style fma chain, ascending c
            float t = fmaf(pw[o * 4 + 0], xv0, 0.0f);
            t = fmaf(pw[o * 4 + 1], xv1, t);
            t = fmaf(pw[o * 4 + 2], xv2, t);
            t = fmaf(pw[o * 4 + 3], xv3, t);
            q[p][o] = __fadd_rn(t, pb[o]);
        }
        // ||q||^2 numpy-style: rounded products, sequential adds
        float s = __fmul_rn(q[p][0], q[p][0]);
        s = __fadd_rn(s, __fmul_rn(q[p][1], q[p][1]));
        s = __fadd_rn(s, __fmul_rn(q[p][2], q[p][2]));
        s = __fadd_rn(s, __fmul_rn(q[p][3], q[p][3]));
        qq[p] = s;
    }

    // ---- scan this block's K-slice: lane handles k = k0+lane, +64, ... (32 iters) ----
    float best[8];
    int   bi[8];
#pragma unroll
    for (int p = 0; p < 8; ++p) { best[p] = __int_as_float(0x7f800000); bi[p] = 0; }

    const float4* cb4 = (const float4*)cb;

    for (int k = k0 + lane; k < k0 + SLICE_K; k += 64) {
        float4 e = cb4[k];
        // codebook norm, numpy-style rounding (identical to reference's sum(cb*cb))
        float nk = __fmul_rn(e.x, e.x);
        nk = __fadd_rn(nk, __fmul_rn(e.y, e.y));
        nk = __fadd_rn(nk, __fmul_rn(e.z, e.z));
        nk = __fadd_rn(nk, __fmul_rn(e.w, e.w));
#pragma unroll
        for (int p = 0; p < 8; ++p) {
            float d = fmaf(q[p][0], e.x, 0.0f);       // BLAS-style dot, ascending c
            d = fmaf(q[p][1], e.y, d);
            d = fmaf(q[p][2], e.z, d);
            d = fmaf(q[p][3], e.w, d);
            // reference assoc: (qq - 2*dot) + nk ; 2*dot exact, fma == sub rounding
            float s = __fadd_rn(fmaf(-2.0f, d, qq[p]), nk);
            if (s < best[p]) { best[p] = s; bi[p] = k; }  // strict <: first k wins
        }
    }

    // ---- publish per-lane winners; min packed key == np.argmin semantics ----
#pragma unroll
    for (int p = 0; p < 8; ++p)
        keys[wave][p][lane] =
            ((unsigned long long)fkey(best[p]) << 32) | (unsigned int)bi[p];
    __syncthreads();

    if (tid < 32) {
        int w = tid >> 3, p = tid & 7;
        unsigned long long bk = ~0ull;
#pragma unroll 4
        for (int i = 0; i < 64; ++i) {
            unsigned long long c = keys[w][p][i ^ tid];    // XOR spreads LDS banks
            bk = (c < bk) ? c : bk;
        }
        int pos = (pg * 4 + w) * 8 + p;
        keys_ws[pos * SLICES + slice] = bk;
    }
}

__global__ __launch_bounds__(256) void vq_epi(const float* __restrict__ x,
                                              const float* __restrict__ cb,
                                              const float* __restrict__ qw,
                                              const float* __restrict__ qb,
                                              const unsigned long long* __restrict__ keys_ws,
                                              float* __restrict__ lossp,
                                              float* __restrict__ out) {
    __shared__ float red[256];
    const int tid = threadIdx.x;
    const int pos = blockIdx.x * 256 + tid;   // 64 blocks x 256 = NPOS

    // combine the 4 slice winners (min key = global first-occurrence argmin)
    unsigned long long bk = keys_ws[pos * SLICES + 0];
    unsigned long long c1 = keys_ws[pos * SLICES + 1];
    unsigned long long c2 = keys_ws[pos * SLICES + 2];
    unsigned long long c3 = keys_ws[pos * SLICES + 3];
    bk = (c1 < bk) ? c1 : bk;
    bk = (c2 < bk) ? c2 : bk;
    bk = (c3 < bk) ? c3 : bk;
    int idx = (int)(bk & 0xFFFFFFFFull);

    int b = pos >> 12, n = pos & 4095;
    const float4* cb4 = (const float4*)cb;
    float4 e = cb4[idx];

    const float* xb = x + b * (CC * NN) + n;
    float xv0 = xb[0], xv1 = xb[NN], xv2 = xb[2 * NN], xv3 = xb[3 * NN];

    // straight-through (forward): st = x + (quant - x), matching reference fp ops
    float s0 = __fadd_rn(xv0, __fsub_rn(e.x, xv0));
    float s1 = __fadd_rn(xv1, __fsub_rn(e.y, xv1));
    float s2 = __fadd_rn(xv2, __fsub_rn(e.z, xv2));
    float s3 = __fadd_rn(xv3, __fsub_rn(e.w, xv3));

    // postquant 1x1 conv -> float32 output (coalesced per-o: consecutive n)
#pragma unroll
    for (int o = 0; o < 4; ++o) {
        float t = fmaf(qw[o * 4 + 0], s0, 0.0f);
        t = fmaf(qw[o * 4 + 1], s1, t);
        t = fmaf(qw[o * 4 + 2], s2, t);
        t = fmaf(qw[o * 4 + 3], s3, t);
        t = __fadd_rn(t, qb[o]);
        out[b * (CC * NN) + o * NN + n] = t;
    }

    // index output as float32
    out[OUT_IDX + b * NN + n] = (float)idx;

    // loss partial: sum_c (quant - x)^2 (both losses identical in forward)
    float d0 = __fsub_rn(e.x, xv0), d1 = __fsub_rn(e.y, xv1);
    float d2 = __fsub_rn(e.z, xv2), d3 = __fsub_rn(e.w, xv3);
    float lp = __fmul_rn(d0, d0);
    lp = __fadd_rn(lp, __fmul_rn(d1, d1));
    lp = __fadd_rn(lp, __fmul_rn(d2, d2));
    lp = __fadd_rn(lp, __fmul_rn(d3, d3));

    red[tid] = lp;
    __syncthreads();
#pragma unroll
    for (int s = 128; s > 0; s >>= 1) {
        if (tid < s) red[tid] += red[tid + s];
        __syncthreads();
    }
    if (tid == 0) lossp[blockIdx.x] = red[0];
}

__global__ void vq_fin(const float* __restrict__ lossp, float* __restrict__ out) {
    if (threadIdx.x == 0) {
        float s = 0.0f;
        for (int i = 0; i < 64; ++i) s += lossp[i];
        s *= (1.0f / (float)(NPOS * CC));
        out[OUT_LOSS + 0] = s;
        out[OUT_LOSS + 1] = s;
    }
}

extern "C" void kernel_launch(void* const* d_in, const int* in_sizes, int n_in,
                              void* d_out, int out_size, void* d_ws, size_t ws_size,
                              hipStream_t stream) {
    const float* x  = (const float*)d_in[0];
    const float* pw = (const float*)d_in[1];
    const float* pb = (const float*)d_in[2];
    const float* cb = (const float*)d_in[3];
    const float* qw = (const float*)d_in[4];
    const float* qb = (const float*)d_in[5];
    float* out = (float*)d_out;

    unsigned long long* keys_ws = (unsigned long long*)d_ws;
    float* lossp = (float*)((char*)d_ws + LOSS_BYTE_OFF);

    vq_search<<<(NPOS / 32) * SLICES, 256, 0, stream>>>(x, pw, pb, cb, keys_ws);
    vq_epi<<<NPOS / 256, 256, 0, stream>>>(x, cb, qw, qb, keys_ws, lossp, out);
    vq_fin<<<1, 64, 0, stream>>>(lossp, out);
}